// Round 15
// baseline (125.058 us; speedup 1.0000x reference)
//
#include <hip/hip_runtime.h>
#include <math.h>

// AtomQueryFieldNet: NQ=4096, NA=512, pair MLP 18->64->64->32->1, cutoff mask,
// per-query 3-vector reduction, 3->64->3 head.
//
// R15: 4 queries per block — amortize fixed costs, pooled chunks, parallel heads.
//  - R14 post-mortem: K=16 in-register chain killed bank conflicts (1.9M->0)
//    but per-query fixed costs dominate: weight preload (~1us), 3 barriers,
//    serial head, per 4096 blocks; VGPR=76 shows weights refetch in-loop.
//  - R15: grid 1024 x 256 (4 waves). Wave w ballot-compacts query blockIdx*4+w
//    (full 512 atoms, zero barriers). ONE barrier -> all waves pull 32-pair
//    chunks round-robin from the COMBINED pool (~24 chunks, imbalance smoothed
//    over 4 queries). ONE barrier -> 4 heads in parallel (wave w -> query w).
//    Barriers per 4 queries: 12 -> 2; preloads: 4 -> 1.
//  - Hot loop = R14: K=16 MFMA chaining (C/D row = next B-frag k), no LDS
//    exchange, fused L4 + accumulation (acc per query, uniform if-chain).
//  - LDS ~28.4KB -> 5 blocks/CU cap. fp16 in / fp32 accum; absmax ~0.0156.

typedef _Float16 f16x4 __attribute__((ext_vector_type(4)));
typedef _Float16 f16x2 __attribute__((ext_vector_type(2)));
typedef float    f32x4 __attribute__((ext_vector_type(4)));

#define CAP 352   // max in-range atoms/query (binomial mean 268, +7.4 sigma)
#define NT  2     // tiles (16 pairs) interleaved per chunk
#define QPB 4     // queries per block (= waves per block)

// ---- repack: weights -> K=16 MFMA A-fragment order in d_ws (see R14) ----
__global__ __launch_bounds__(64) void repack_kernel(
    const float* __restrict__ W1, const float* __restrict__ b1,
    const float* __restrict__ W2, const float* __restrict__ b2,
    const float* __restrict__ W3, const float* __restrict__ b3,
    const float* __restrict__ W4, char* __restrict__ ws)
{
    const int b = blockIdx.x, l = threadIdx.x;
    const int col = l & 15, quad = l >> 4;
    if (b < 32) {
        f16x4 v;
        #pragma unroll
        for (int j = 0; j < 4; ++j) {
            float x;
            if (b < 8) {
                const int kc = b >> 2, mt = b & 3;
                const int k = kc*16 + quad*4 + j;
                x = (k < 18) ? W1[k*64 + mt*16 + col]
                             : (k == 18 ? b1[mt*16 + col] : 0.0f);
            } else if (b < 24) {
                const int idx = b - 8, kc = idx >> 2, mt = idx & 3;
                const int k = kc*16 + quad*4 + j;
                x = W2[k*64 + mt*16 + col];
            } else {
                const int idx = b - 24, kc = idx >> 1, mt = idx & 1;
                const int k = kc*16 + quad*4 + j;
                x = W3[k*32 + mt*16 + col];
            }
            v[j] = (_Float16)x;
        }
        *(f16x4*)(ws + (b*64 + l)*8) = v;
    } else {
        const int d = b - 32;
        float o[4];
        #pragma unroll
        for (int rr = 0; rr < 4; ++rr) {
            const int idx = quad*4 + rr;
            if (d < 4)      o[rr] = b2[d*16 + idx];
            else if (d < 6) o[rr] = b3[(d-4)*16 + idx];
            else            o[rr] = W4[(d-6)*16 + idx];
        }
        *(float4*)(ws + 16384 + (d*64 + l)*16) = make_float4(o[0],o[1],o[2],o[3]);
    }
}

__device__ __forceinline__ f16x4 relu_cvt(f32x4 c) {
    return f16x4{(_Float16)fmaxf(c[0],0.f), (_Float16)fmaxf(c[1],0.f),
                 (_Float16)fmaxf(c[2],0.f), (_Float16)fmaxf(c[3],0.f)};
}

__global__ __launch_bounds__(256, 1) void aqfn_kernel(
    const float* __restrict__ atom_pos,   // (512,3)
    const float* __restrict__ atom_feat,  // (512,2)
    const float* __restrict__ query_pos,  // (4096,3)
    const float* __restrict__ b4,         // (1)
    const float* __restrict__ W5, const float* __restrict__ b5,  // (3,64),(64)
    const float* __restrict__ W6, const float* __restrict__ b6,  // (64,3),(3)
    const char*  __restrict__ ws,         // repacked weights
    float* __restrict__ out)              // (4096,3)
{
    __shared__ __align__(16) float4 rbuf[QPB][CAP];   // per-query lists
    __shared__ __align__(16) f16x2  fbuf[QPB][CAP];
    __shared__ float wred[4][QPB][3];
    __shared__ int   cnt[QPB];

    const int tid  = threadIdx.x;
    const int wave = __builtin_amdgcn_readfirstlane(tid >> 6);
    const int lane = tid & 63;
    const int col  = lane & 15;
    const int quad = lane >> 4;

    // ---- fragment preload (once per block = per 4 queries) ----
    const f16x4*  wsf = (const f16x4*)ws;
    const float4* wsb = (const float4*)(ws + 16384);
    f16x4 w1f[2][4], w2f[4][4], w3f[4][2];
    #pragma unroll
    for (int kc = 0; kc < 2; ++kc)
        #pragma unroll
        for (int mt = 0; mt < 4; ++mt) w1f[kc][mt] = wsf[(kc*4 + mt)*64 + lane];
    #pragma unroll
    for (int kc = 0; kc < 4; ++kc)
        #pragma unroll
        for (int mt = 0; mt < 4; ++mt) w2f[kc][mt] = wsf[(8 + kc*4 + mt)*64 + lane];
    #pragma unroll
    for (int kc = 0; kc < 4; ++kc)
        #pragma unroll
        for (int mt = 0; mt < 2; ++mt) w3f[kc][mt] = wsf[(24 + kc*2 + mt)*64 + lane];
    float4 b2v[4], b3v[2], w4v[2];
    #pragma unroll
    for (int mt = 0; mt < 4; ++mt) b2v[mt] = wsb[mt*64 + lane];
    #pragma unroll
    for (int mt = 0; mt < 2; ++mt) { b3v[mt] = wsb[(4+mt)*64 + lane];
                                     w4v[mt] = wsb[(6+mt)*64 + lane]; }
    const float b4v = b4[0];

    // ---- per-wave compaction: wave w owns query blockIdx*QPB + w ----
    {
        const int qg = blockIdx.x*QPB + wave;
        const float qx = query_pos[qg*3+0];
        const float qy = query_pos[qg*3+1];
        const float qz = query_pos[qg*3+2];
        int c = 0;
        #pragma unroll 1
        for (int it = 0; it < 8; ++it) {
            const int a = it*64 + lane;
            const float rx = qx - atom_pos[a*3+0];
            const float ry = qy - atom_pos[a*3+1];
            const float rz = qz - atom_pos[a*3+2];
            const float ex = __fadd_rn(rx, 1e-12f);
            const float ey = __fadd_rn(ry, 1e-12f);
            const float ez = __fadd_rn(rz, 1e-12f);
            const float dd = __fadd_rn(__fadd_rn(__fmul_rn(ex,ex), __fmul_rn(ey,ey)),
                                       __fmul_rn(ez,ez));
            const float dist = sqrtf(dd);
            const bool  in   = (dist <= 6.0f);
            const unsigned long long m = __ballot(in);
            const int p = c + (int)__popcll(m & ((1ull << lane) - 1ull));
            if (in && p < CAP) {
                rbuf[wave][p] = make_float4(rx, ry, rz, dist);
                fbuf[wave][p] = f16x2{(_Float16)atom_feat[a*2+0],
                                      (_Float16)atom_feat[a*2+1]};
            }
            c += (int)__popcll(m);
        }
        if (c > CAP) c = CAP;
        if (lane == 0) cnt[wave] = c;
    }
    __syncthreads();

    // chunk pool over all QPB queries
    int cntv[QPB], nch[QPB], cum[QPB];
    int ntot = 0;
    #pragma unroll
    for (int w = 0; w < QPB; ++w) {
        cntv[w] = cnt[w];
        nch[w]  = (cntv[w] + (NT*16 - 1)) / (NT*16);
        cum[w]  = ntot;
        ntot   += nch[w];
    }

    float acc[QPB][3] = {{0,0,0},{0,0,0},{0,0,0},{0,0,0}};

    #pragma unroll 1
    for (int g = wave; g < ntot; g += 4) {
        // wave-uniform chunk -> (query cq, local chunk lc)
        int cq = QPB - 1;
        #pragma unroll
        for (int w = QPB - 2; w >= 0; --w)
            if (g < cum[w+1]) cq = w;
        const int lc    = g - cum[cq];
        const int count = cntv[cq];
        const float4* __restrict__ rb = &rbuf[cq][0];
        const f16x2*  __restrict__ fb = &fbuf[cq][0];
        const int row0 = lc * (NT*16);

        float4 rv[NT]; f16x2 ffv[NT];
        #pragma unroll
        for (int u = 0; u < NT; ++u) {
            int pr = row0 + u*16 + col;
            if (pr >= count) pr = count - 1;
            rv[u]  = rb[pr];
            ffv[u] = fb[pr];
        }

        // X B-frags (K=16 chunks): xa[u][kc][j], k = kc*16 + quad*4 + j
        f16x4 xa[NT][2];
        #pragma unroll
        for (int u = 0; u < NT; ++u) {
            const float dist = rv[u].w;
            #pragma unroll
            for (int kc = 0; kc < 2; ++kc)
                #pragma unroll
                for (int j = 0; j < 4; ++j) {
                    const int k = kc*16 + quad*4 + j;
                    const float tt = dist - 0.4f * (float)(k - 2);  // centers linspace(0,6,16)
                    float v = __expf(-10.0f * tt * tt);
                    v = (k < 18) ? v : 0.0f;
                    _Float16 xv = (_Float16)v;
                    if (k == 18) xv = (_Float16)1.0f;   // bias slot (b1 in W1)
                    if (k == 0)  xv = ffv[u][0];
                    if (k == 1)  xv = ffv[u][1];
                    xa[u][kc][j] = xv;
                }
        }

        // ---- L1: output rows mt*16+quad*4+rr == next layer's B-frag kc=mt ----
        f16x4 a2[NT][4];
        #pragma unroll
        for (int u = 0; u < NT; ++u)
            #pragma unroll
            for (int mt = 0; mt < 4; ++mt) {
                f32x4 c = {0.f, 0.f, 0.f, 0.f};
                c = __builtin_amdgcn_mfma_f32_16x16x16f16(w1f[0][mt], xa[u][0], c, 0, 0, 0);
                c = __builtin_amdgcn_mfma_f32_16x16x16f16(w1f[1][mt], xa[u][1], c, 0, 0, 0);
                a2[u][mt] = relu_cvt(c);
            }

        // ---- L2 ----
        f16x4 a3[NT][4];
        #pragma unroll
        for (int u = 0; u < NT; ++u)
            #pragma unroll
            for (int mt = 0; mt < 4; ++mt) {
                f32x4 c = {b2v[mt].x, b2v[mt].y, b2v[mt].z, b2v[mt].w};
                #pragma unroll
                for (int kc = 0; kc < 4; ++kc)
                    c = __builtin_amdgcn_mfma_f32_16x16x16f16(w2f[kc][mt], a2[u][kc], c, 0, 0, 0);
                a3[u][mt] = relu_cvt(c);
            }

        // ---- L3 + L4 partial + quad-reduce + fused accumulation ----
        #pragma unroll
        for (int u = 0; u < NT; ++u) {
            float s = 0.f;
            #pragma unroll
            for (int mt = 0; mt < 2; ++mt) {
                f32x4 c = {b3v[mt].x, b3v[mt].y, b3v[mt].z, b3v[mt].w};
                #pragma unroll
                for (int kc = 0; kc < 4; ++kc)
                    c = __builtin_amdgcn_mfma_f32_16x16x16f16(w3f[kc][mt], a3[u][kc], c, 0, 0, 0);
                const float* wv = &w4v[mt].x;
                #pragma unroll
                for (int rr = 0; rr < 4; ++rr)
                    s = fmaf(fmaxf(c[rr], 0.f), wv[rr], s);
            }
            s += __shfl_xor(s, 16);
            s += __shfl_xor(s, 32);
            s += b4v;
            const int  p2  = row0 + u*16 + col;
            const bool vld = (p2 < count);
            const float inv = __builtin_amdgcn_rcpf(rv[u].w + 1e-12f);
            const float wm  = vld ? (s * inv) : 0.f;
            // wave-uniform query index -> explicit if-chain (no dyn reg indexing)
            if      (cq == 0) { acc[0][0] = fmaf(wm, rv[u].x, acc[0][0]);
                                acc[0][1] = fmaf(wm, rv[u].y, acc[0][1]);
                                acc[0][2] = fmaf(wm, rv[u].z, acc[0][2]); }
            else if (cq == 1) { acc[1][0] = fmaf(wm, rv[u].x, acc[1][0]);
                                acc[1][1] = fmaf(wm, rv[u].y, acc[1][1]);
                                acc[1][2] = fmaf(wm, rv[u].z, acc[1][2]); }
            else if (cq == 2) { acc[2][0] = fmaf(wm, rv[u].x, acc[2][0]);
                                acc[2][1] = fmaf(wm, rv[u].y, acc[2][1]);
                                acc[2][2] = fmaf(wm, rv[u].z, acc[2][2]); }
            else              { acc[3][0] = fmaf(wm, rv[u].x, acc[3][0]);
                                acc[3][1] = fmaf(wm, rv[u].y, acc[3][1]);
                                acc[3][2] = fmaf(wm, rv[u].z, acc[3][2]); }
        }
    }

    // ---- butterflies (x0.25: each pair counted by 4 quads) ----
    #pragma unroll
    for (int w = 0; w < QPB; ++w)
        #pragma unroll
        for (int d = 0; d < 3; ++d) {
            float v = acc[w][d];
            #pragma unroll
            for (int off = 1; off < 64; off <<= 1) v += __shfl_xor(v, off);
            if (lane == 0) wred[wave][w][d] = v * 0.25f;
        }
    __syncthreads();

    // ---- heads in parallel: wave w -> query blockIdx*QPB + w ----
    {
        const int w = wave;
        const float v0 = wred[0][w][0] + wred[1][w][0] + wred[2][w][0] + wred[3][w][0];
        const float v1 = wred[0][w][1] + wred[1][w][1] + wred[2][w][1] + wred[3][w][1];
        const float v2 = wred[0][w][2] + wred[1][w][2] + wred[2][w][2] + wred[3][w][2];
        float th = fmaf(v0, W5[lane],
                   fmaf(v1, W5[64+lane],
                   fmaf(v2, W5[128+lane], b5[lane])));
        th = fmaxf(th, 0.f);
        float o0 = th * W6[lane*3+0];
        float o1 = th * W6[lane*3+1];
        float o2 = th * W6[lane*3+2];
        #pragma unroll
        for (int off = 1; off < 64; off <<= 1) {
            o0 += __shfl_xor(o0, off);
            o1 += __shfl_xor(o1, off);
            o2 += __shfl_xor(o2, off);
        }
        if (lane == 0) {
            const int qo = blockIdx.x*QPB + w;
            out[qo*3+0] = o0 + b6[0];
            out[qo*3+1] = o1 + b6[1];
            out[qo*3+2] = o2 + b6[2];
        }
    }
}

extern "C" void kernel_launch(void* const* d_in, const int* in_sizes, int n_in,
                              void* d_out, int out_size, void* d_ws, size_t ws_size,
                              hipStream_t stream) {
    const float* atom_pos  = (const float*)d_in[0];
    const float* atom_feat = (const float*)d_in[1];
    const float* query_pos = (const float*)d_in[2];
    const float* W1 = (const float*)d_in[3];  const float* b1 = (const float*)d_in[4];
    const float* W2 = (const float*)d_in[5];  const float* b2 = (const float*)d_in[6];
    const float* W3 = (const float*)d_in[7];  const float* b3 = (const float*)d_in[8];
    const float* W4 = (const float*)d_in[9];  const float* b4 = (const float*)d_in[10];
    const float* W5 = (const float*)d_in[11]; const float* b5 = (const float*)d_in[12];
    const float* W6 = (const float*)d_in[13]; const float* b6 = (const float*)d_in[14];
    float* out = (float*)d_out;
    char*  ws  = (char*)d_ws;   // 16KB frags + 8KB biases

    hipLaunchKernelGGL(repack_kernel, dim3(40), dim3(64), 0, stream,
                       W1, b1, W2, b2, W3, b3, W4, ws);
    hipLaunchKernelGGL(aqfn_kernel, dim3(4096 / QPB), dim3(256), 0, stream,
                       atom_pos, atom_feat, query_pos, b4, W5, b5, W6, b6,
                       (const char*)ws, out);
}